// Round 2
// baseline (510.209 us; speedup 1.0000x reference)
//
#include <hip/hip_runtime.h>
#include <utility>

// ---------------------------------------------------------------------------
// Compile-time Clebsch-Gordan coefficients (Racah formula), fp64 -> fp32.
// Split into 4 tables (one per l1) to stay under clang's constexpr step limit.
// ---------------------------------------------------------------------------
namespace cg {

constexpr double FACT[14] = {
  1.0, 1.0, 2.0, 6.0, 24.0, 120.0, 720.0, 5040.0, 40320.0, 362880.0,
  3628800.0, 39916800.0, 479001600.0, 6227020800.0
};

constexpr double csqrt(double x){
  double g = x > 1.0 ? x : 1.0;
  for (int i = 0; i < 64; ++i) g = 0.5 * (g + x / g);
  return g;
}
constexpr int cabs_(int x){ return x < 0 ? -x : x; }
constexpr int imax_(int a, int b){ return a > b ? a : b; }
constexpr int imin_(int a, int b){ return a < b ? a : b; }

constexpr double cg_coeff(int j1,int m1,int j2,int m2,int j,int m){
  if (m1 + m2 != m || j < cabs_(j1 - j2) || j > j1 + j2) return 0.0;
  double pre = csqrt((2.0*j + 1.0) * FACT[j1+j2-j] * FACT[j+j1-j2] * FACT[j+j2-j1]
                     / FACT[j1+j2+j+1]);
  pre *= csqrt(FACT[j+m] * FACT[j-m] * FACT[j1+m1] * FACT[j1-m1]
             * FACT[j2+m2] * FACT[j2-m2]);
  double s = 0.0;
  for (int k = 0; k <= j1 + j2 - j; ++k){
    int d2 = j1 - m1 - k, d3 = j2 + m2 - k, d4 = j - j2 + m1 + k, d5 = j - j1 - m2 + k;
    if (d2 < 0 || d3 < 0 || d4 < 0 || d5 < 0) continue;
    double denom = FACT[k] * FACT[j1+j2-j-k] * FACT[d2] * FACT[d3] * FACT[d4] * FACT[d5];
    s += ((k & 1) ? -1.0 : 1.0) / denom;
  }
  return pre * s;
}

struct Tab1 { float c[4][7][7][7]; };  // [l2][l][m1+l1][m2+l2] for fixed l1
constexpr Tab1 make_tab1(int l1){
  Tab1 t{};
  for (int l2 = 0; l2 < 4; ++l2)
    for (int l = 0; l < 7; ++l)
      for (int i1 = 0; i1 < 2*l1 + 1; ++i1)
        for (int i2 = 0; i2 < 2*l2 + 1; ++i2){
          int m1 = i1 - l1, m2 = i2 - l2, m = m1 + m2;
          if (m < -l || m > l) continue;
          t.c[l2][l][i1][i2] = (float)cg_coeff(l1, m1, l2, m2, l, m);
        }
  return t;
}
constexpr Tab1 T0 = make_tab1(0);
constexpr Tab1 T1 = make_tab1(1);
constexpr Tab1 T2 = make_tab1(2);
constexpr Tab1 T3 = make_tab1(3);
constexpr float getc(int l1,int l2,int l,int i1,int i2){
  return l1 == 0 ? T0.c[l2][l][i1][i2]
       : l1 == 1 ? T1.c[l2][l][i1][i2]
       : l1 == 2 ? T2.c[l2][l][i1][i2]
       :           T3.c[l2][l][i1][i2];
}

// Fragment (l1,l2) pair lists in gelib order (l1-major), per output l.
constexpr int NP[7]    = {4, 9, 11, 10, 6, 3, 1};          // tau_l
constexpr int PBASE[7] = {0, 4, 31, 86, 156, 210, 243};    // part base, in (re,im)-pair units
constexpr int IOFF[4]  = {0, 1, 4, 9};                     // input offset per l (pair units)
constexpr int P1[7][11] = {
  {0,1,2,3,0,0,0,0,0,0,0},
  {0,1,1,1,2,2,2,3,3,0,0},
  {0,1,1,1,2,2,2,2,3,3,3},
  {0,1,1,2,2,2,3,3,3,3,0},
  {1,2,2,3,3,3,0,0,0,0,0},
  {2,3,3,0,0,0,0,0,0,0,0},
  {3,0,0,0,0,0,0,0,0,0,0}
};
constexpr int P2[7][11] = {
  {0,1,2,3,0,0,0,0,0,0,0},
  {1,0,1,2,1,2,3,2,3,0,0},
  {2,1,2,3,0,1,2,3,1,2,3},
  {3,2,3,1,2,3,0,1,2,3,0},
  {3,2,3,1,2,3,0,0,0,0,0},
  {3,2,3,0,0,0,0,0,0,0,0},
  {3,0,0,0,0,0,0,0,0,0,0}
};

} // namespace cg

// ---------------------------------------------------------------------------
// static_for: guarantees every loop index is a compile-time constant
// ---------------------------------------------------------------------------
template<class F, int... Is>
__device__ __forceinline__ void sfor_impl(F&& f, std::integer_sequence<int, Is...>){
  (f(std::integral_constant<int, Is>{}), ...);
}
template<int N, class F>
__device__ __forceinline__ void sfor(F&& f){
  sfor_impl(static_cast<F&&>(f), std::make_integer_sequence<int, N>{});
}

// Store a row of N floats at float-offset R0 (o is 2KB-aligned), using the
// widest compile-time-aligned vector stores available.
template<int R0, int N>
struct RowStoreF {
  template<int I>
  __device__ static __forceinline__ void step(float* o, const float* row){
    if constexpr (I < N){
      constexpr int rem = N - I;
      if constexpr ((((R0 + I) & 3) == 0) && rem >= 4){
        float4 v; v.x = row[I]; v.y = row[I+1]; v.z = row[I+2]; v.w = row[I+3];
        *reinterpret_cast<float4*>(o + R0 + I) = v;
        step<I+4>(o, row);
      } else if constexpr ((((R0 + I) & 1) == 0) && rem >= 2){
        float2 v; v.x = row[I]; v.y = row[I+1];
        *reinterpret_cast<float2*>(o + R0 + I) = v;
        step<I+2>(o, row);
      } else {
        o[R0 + I] = row[I];
        step<I+1>(o, row);
      }
    }
  }
  __device__ static __forceinline__ void run(float* o, const float* row){
    step<0>(o, row);
  }
};

// One thread per batch element: 32 fp32 in, ~5K fp32 VALU ops, 512 fp32 out.
__global__ __launch_bounds__(256) void cgprod_kernel(
    const float* __restrict__ x0, const float* __restrict__ x1,
    const float* __restrict__ x2, const float* __restrict__ x3,
    float* __restrict__ out, int B)
{
  const int b = blockIdx.x * blockDim.x + threadIdx.x;
  if (b >= B) return;

  float xr[16], xi[16];  // per-l pair offsets 0,1,4,9 (sizes 1,3,5,7)
  { float2 v = *reinterpret_cast<const float2*>(x0 + (size_t)b * 2);
    xr[0] = v.x; xi[0] = v.y; }
  { const float2* p = reinterpret_cast<const float2*>(x1 + (size_t)b * 6);
    sfor<3>([&](auto I){ constexpr int i = decltype(I)::value;
      float2 v = p[i]; xr[1+i] = v.x; xi[1+i] = v.y; }); }
  { const float2* p = reinterpret_cast<const float2*>(x2 + (size_t)b * 10);
    sfor<5>([&](auto I){ constexpr int i = decltype(I)::value;
      float2 v = p[i]; xr[4+i] = v.x; xi[4+i] = v.y; }); }
  { const float2* p = reinterpret_cast<const float2*>(x3 + (size_t)b * 14);
    sfor<7>([&](auto I){ constexpr int i = decltype(I)::value;
      float2 v = p[i]; xr[9+i] = v.x; xi[9+i] = v.y; }); }

  float* o = out + (size_t)b * 512;  // 512 fp32 per element, 2KB-aligned

  sfor<7>([&](auto LC){
    constexpr int l   = decltype(LC)::value;
    constexpr int tau = cg::NP[l];
    sfor<2*l + 1>([&](auto MC){
      constexpr int mi = decltype(MC)::value;
      constexpr int m  = mi - l;
      float row[2 * tau];
      sfor<tau>([&](auto TC){
        constexpr int t  = decltype(TC)::value;
        constexpr int l1 = cg::P1[l][t];
        constexpr int l2 = cg::P2[l][t];
        constexpr int m1lo = cg::imax_(-l1, m - l2);
        constexpr int m1hi = cg::imin_( l1, m + l2);
        float fr = 0.f, fi = 0.f;
        sfor<m1hi - m1lo + 1>([&](auto KC){
          constexpr int m1 = m1lo + decltype(KC)::value;
          constexpr int m2 = m - m1;
          constexpr float c = cg::getc(l1, l2, l, m1 + l1, m2 + l2);
          if constexpr (c != 0.0f){
            constexpr int ia = cg::IOFF[l1] + m1 + l1;
            constexpr int ib = cg::IOFF[l2] + m2 + l2;
            const float ar = xr[ia], ai = xi[ia];
            const float br = xr[ib], bi = xi[ib];
            const float tr = fmaf(-ai, bi, ar * br);  // re(x_l1 * x_l2)
            const float ti = fmaf( ai, br, ar * bi);  // im(x_l1 * x_l2)
            fr = fmaf(c, tr, fr);
            fi = fmaf(c, ti, fi);
          }
        });
        row[2*t]     = fr;
        row[2*t + 1] = fi;
      });
      RowStoreF<2 * (cg::PBASE[l] + mi * tau), 2 * tau>::run(o, row);
    });
  });
}

extern "C" void kernel_launch(void* const* d_in, const int* in_sizes, int n_in,
                              void* d_out, int out_size, void* d_ws, size_t ws_size,
                              hipStream_t stream)
{
  const float* x0 = (const float*)d_in[0];
  const float* x1 = (const float*)d_in[1];
  const float* x2 = (const float*)d_in[2];
  const float* x3 = (const float*)d_in[3];
  float* out = (float*)d_out;

  const int B = in_sizes[0] / 2;  // x0 is (B, 1, 2)
  const int block = 256;
  const int grid = (B + block - 1) / block;
  cgprod_kernel<<<grid, block, 0, stream>>>(x0, x1, x2, x3, out, B);
}

// Round 3
// 372.004 us; speedup vs baseline: 1.3715x; 1.3715x over previous
//
#include <hip/hip_runtime.h>
#include <utility>

// ---------------------------------------------------------------------------
// Compile-time Clebsch-Gordan coefficients (Racah formula), fp64 -> fp32.
// Split into 4 tables (one per l1) to stay under clang's constexpr step limit.
// ---------------------------------------------------------------------------
namespace cg {

constexpr double FACT[14] = {
  1.0, 1.0, 2.0, 6.0, 24.0, 120.0, 720.0, 5040.0, 40320.0, 362880.0,
  3628800.0, 39916800.0, 479001600.0, 6227020800.0
};

constexpr double csqrt(double x){
  double g = x > 1.0 ? x : 1.0;
  for (int i = 0; i < 64; ++i) g = 0.5 * (g + x / g);
  return g;
}
constexpr int cabs_(int x){ return x < 0 ? -x : x; }
constexpr int imax_(int a, int b){ return a > b ? a : b; }
constexpr int imin_(int a, int b){ return a < b ? a : b; }

constexpr double cg_coeff(int j1,int m1,int j2,int m2,int j,int m){
  if (m1 + m2 != m || j < cabs_(j1 - j2) || j > j1 + j2) return 0.0;
  double pre = csqrt((2.0*j + 1.0) * FACT[j1+j2-j] * FACT[j+j1-j2] * FACT[j+j2-j1]
                     / FACT[j1+j2+j+1]);
  pre *= csqrt(FACT[j+m] * FACT[j-m] * FACT[j1+m1] * FACT[j1-m1]
             * FACT[j2+m2] * FACT[j2-m2]);
  double s = 0.0;
  for (int k = 0; k <= j1 + j2 - j; ++k){
    int d2 = j1 - m1 - k, d3 = j2 + m2 - k, d4 = j - j2 + m1 + k, d5 = j - j1 - m2 + k;
    if (d2 < 0 || d3 < 0 || d4 < 0 || d5 < 0) continue;
    double denom = FACT[k] * FACT[j1+j2-j-k] * FACT[d2] * FACT[d3] * FACT[d4] * FACT[d5];
    s += ((k & 1) ? -1.0 : 1.0) / denom;
  }
  return pre * s;
}

struct Tab1 { float c[4][7][7][7]; };  // [l2][l][m1+l1][m2+l2] for fixed l1
constexpr Tab1 make_tab1(int l1){
  Tab1 t{};
  for (int l2 = 0; l2 < 4; ++l2)
    for (int l = 0; l < 7; ++l)
      for (int i1 = 0; i1 < 2*l1 + 1; ++i1)
        for (int i2 = 0; i2 < 2*l2 + 1; ++i2){
          int m1 = i1 - l1, m2 = i2 - l2, m = m1 + m2;
          if (m < -l || m > l) continue;
          t.c[l2][l][i1][i2] = (float)cg_coeff(l1, m1, l2, m2, l, m);
        }
  return t;
}
constexpr Tab1 T0 = make_tab1(0);
constexpr Tab1 T1 = make_tab1(1);
constexpr Tab1 T2 = make_tab1(2);
constexpr Tab1 T3 = make_tab1(3);
constexpr float getc(int l1,int l2,int l,int i1,int i2){
  return l1 == 0 ? T0.c[l2][l][i1][i2]
       : l1 == 1 ? T1.c[l2][l][i1][i2]
       : l1 == 2 ? T2.c[l2][l][i1][i2]
       :           T3.c[l2][l][i1][i2];
}

// Fragment (l1,l2) pair lists in gelib order (l1-major), per output l.
constexpr int NP[7]    = {4, 9, 11, 10, 6, 3, 1};          // tau_l
constexpr int IOFF[4]  = {0, 1, 4, 9};                     // input offset per l (pair units)
constexpr int P1[7][11] = {
  {0,1,2,3,0,0,0,0,0,0,0},
  {0,1,1,1,2,2,2,3,3,0,0},
  {0,1,1,1,2,2,2,2,3,3,3},
  {0,1,1,2,2,2,3,3,3,3,0},
  {1,2,2,3,3,3,0,0,0,0,0},
  {2,3,3,0,0,0,0,0,0,0,0},
  {3,0,0,0,0,0,0,0,0,0,0}
};
constexpr int P2[7][11] = {
  {0,1,2,3,0,0,0,0,0,0,0},
  {1,0,1,2,1,2,3,2,3,0,0},
  {2,1,2,3,0,1,2,3,1,2,3},
  {3,2,3,1,2,3,0,1,2,3,0},
  {3,2,3,1,2,3,0,0,0,0,0},
  {3,2,3,0,0,0,0,0,0,0,0},
  {3,0,0,0,0,0,0,0,0,0,0}
};

// ---- Row table: 49 output rows (l, mi), each 2*NP[l] floats, laid out
// consecutively in the 512-float per-element output. ----
constexpr int ROWN = 49;
struct Rows { int l[ROWN]; int mi[ROWN]; int off[ROWN]; int sz[ROWN]; };
constexpr Rows make_rows(){
  Rows r{}; int idx = 0; int off = 0;
  for (int l = 0; l < 7; ++l)
    for (int mi = 0; mi < 2*l + 1; ++mi){
      r.l[idx] = l; r.mi[idx] = mi; r.off[idx] = off; r.sz[idx] = 2*NP[l];
      off += 2*NP[l]; ++idx;
    }
  return r;
}
constexpr Rows RW = make_rows();

// ---- Chunk table: greedy grouping of whole rows, <= CAP floats/element,
// so a chunk of all 256 threads fits in static LDS. ----
constexpr int CAP = 63;
struct Chunks { int n; int first[20]; int cnt[20]; int start[20]; int size[20]; };
constexpr Chunks make_chunks(){
  Chunks c{}; int i = 0; int n = 0;
  while (i < ROWN){
    int first = i, sz = 0;
    while (i < ROWN && sz + RW.sz[i] <= CAP){ sz += RW.sz[i]; ++i; }
    c.first[n] = first; c.cnt[n] = i - first;
    c.start[n] = RW.off[first]; c.size[n] = sz; ++n;
  }
  c.n = n; return c;
}
constexpr Chunks CH = make_chunks();

} // namespace cg

// ---------------------------------------------------------------------------
// static_for: guarantees every loop index is a compile-time constant
// ---------------------------------------------------------------------------
template<class F, int... Is>
__device__ __forceinline__ void sfor_impl(F&& f, std::integer_sequence<int, Is...>){
  (f(std::integral_constant<int, Is>{}), ...);
}
template<int N, class F>
__device__ __forceinline__ void sfor(F&& f){
  sfor_impl(static_cast<F&&>(f), std::make_integer_sequence<int, N>{});
}

// ---------------------------------------------------------------------------
// Kernel: one thread computes one batch element; output staged through LDS
// chunk-by-chunk so every global store instruction is fully coalesced
// (lane i writes float i of a contiguous 256-float span).
// LDS layout lds[j*257 + t]: writes bank=(j+t)%32 (2-way, free), reads
// bank=(j+e)%32 (~2-way). 63*257*4 = 64764 B <= 64 KB static limit.
// ---------------------------------------------------------------------------
__global__ __launch_bounds__(256) void cgprod_kernel(
    const float* __restrict__ x0, const float* __restrict__ x1,
    const float* __restrict__ x2, const float* __restrict__ x3,
    float* __restrict__ out, int B)
{
  __shared__ float lds[cg::CAP * 257];

  const int tid = threadIdx.x;
  const int block_base = blockIdx.x * 256;
  const int b = block_base + tid;
  const int bc = b < B ? b : B - 1;   // clamp: all threads must reach barriers

  float xr[16], xi[16];  // per-l pair offsets 0,1,4,9 (sizes 1,3,5,7)
  { float2 v = *reinterpret_cast<const float2*>(x0 + (size_t)bc * 2);
    xr[0] = v.x; xi[0] = v.y; }
  { const float2* p = reinterpret_cast<const float2*>(x1 + (size_t)bc * 6);
    sfor<3>([&](auto I){ constexpr int i = decltype(I)::value;
      float2 v = p[i]; xr[1+i] = v.x; xi[1+i] = v.y; }); }
  { const float2* p = reinterpret_cast<const float2*>(x2 + (size_t)bc * 10);
    sfor<5>([&](auto I){ constexpr int i = decltype(I)::value;
      float2 v = p[i]; xr[4+i] = v.x; xi[4+i] = v.y; }); }
  { const float2* p = reinterpret_cast<const float2*>(x3 + (size_t)bc * 14);
    sfor<7>([&](auto I){ constexpr int i = decltype(I)::value;
      float2 v = p[i]; xr[9+i] = v.x; xi[9+i] = v.y; }); }

  sfor<cg::CH.n>([&](auto CC){
    constexpr int c = decltype(CC)::value;
    constexpr int S = cg::CH.size[c];   // floats per element in this chunk
    constexpr int G = cg::CH.start[c];  // global float offset of chunk start

    // --- compute this chunk's rows, stage into LDS ---
    sfor<cg::CH.cnt[c]>([&](auto RC){
      constexpr int r   = cg::CH.first[c] + decltype(RC)::value;
      constexpr int l   = cg::RW.l[r];
      constexpr int mi  = cg::RW.mi[r];
      constexpr int loc = cg::RW.off[r] - G;  // local float offset in chunk
      constexpr int tau = cg::NP[l];
      constexpr int m   = mi - l;
      sfor<tau>([&](auto TC){
        constexpr int t  = decltype(TC)::value;
        constexpr int l1 = cg::P1[l][t];
        constexpr int l2 = cg::P2[l][t];
        constexpr int m1lo = cg::imax_(-l1, m - l2);
        constexpr int m1hi = cg::imin_( l1, m + l2);
        float fr = 0.f, fi = 0.f;
        sfor<m1hi - m1lo + 1>([&](auto KC){
          constexpr int m1 = m1lo + decltype(KC)::value;
          constexpr int m2 = m - m1;
          constexpr float cc = cg::getc(l1, l2, l, m1 + l1, m2 + l2);
          if constexpr (cc != 0.0f){
            constexpr int ia = cg::IOFF[l1] + m1 + l1;
            constexpr int ib = cg::IOFF[l2] + m2 + l2;
            const float ar = xr[ia], ai = xi[ia];
            const float br = xr[ib], bi = xi[ib];
            const float tr = fmaf(-ai, bi, ar * br);  // re(x_l1 * x_l2)
            const float ti = fmaf( ai, br, ar * bi);  // im(x_l1 * x_l2)
            fr = fmaf(cc, tr, fr);
            fi = fmaf(cc, ti, fi);
          }
        });
        lds[(loc + 2*t    ) * 257 + tid] = fr;
        lds[(loc + 2*t + 1) * 257 + tid] = fi;
      });
    });

    __syncthreads();

    // --- coalesced copy-out: flat f = tid + 256*k over 256*S floats;
    //     e = f / S (element), j = f % S (float within chunk). Incremental
    //     divmod: one magic-div for tid, then add/compare/select per iter. ---
    {
      constexpr int q = 256 / S, rr = 256 % S;
      int e = tid / S;
      int j = tid - e * S;
      for (int k = 0; k < S; ++k){
        const int eb = block_base + e;
        if (eb < B)
          out[(size_t)eb * 512 + (G + j)] = lds[j * 257 + e];
        j += rr; e += q;
        if (j >= S){ j -= S; e += 1; }
      }
    }

    __syncthreads();
  });
}

extern "C" void kernel_launch(void* const* d_in, const int* in_sizes, int n_in,
                              void* d_out, int out_size, void* d_ws, size_t ws_size,
                              hipStream_t stream)
{
  const float* x0 = (const float*)d_in[0];
  const float* x1 = (const float*)d_in[1];
  const float* x2 = (const float*)d_in[2];
  const float* x3 = (const float*)d_in[3];
  float* out = (float*)d_out;

  const int B = in_sizes[0] / 2;  // x0 is (B, 1, 2)
  const int block = 256;
  const int grid = (B + block - 1) / block;
  cgprod_kernel<<<grid, block, 0, stream>>>(x0, x1, x2, x3, out, B);
}